// Round 5
// baseline (6853.135 us; speedup 1.0000x reference)
//
#include <hip/hip_runtime.h>

// ---------------- problem constants ----------------
constexpr int Bn = 128, Tn = 256, An = 16, Ln = 256, Sn = 32, Dn = 512, Hn = 512;
constexpr int STLD = 544;         // hW1t weight row K-stride: [h 512 | z 32]
constexpr int GK   = 576;         // gates K padded: [h 512, z 32, a 16, pad 16]
constexpr int HLP  = 520;         // LDS h/q row stride (padding vs 1024B bank stride)

typedef __bf16 bf16x8 __attribute__((ext_vector_type(8)));
typedef float  f32x4  __attribute__((ext_vector_type(4)));
typedef unsigned short u16;
typedef unsigned long long u64;

__device__ __forceinline__ f32x4 mfma16(bf16x8 a, bf16x8 b, f32x4 c) {
  return __builtin_amdgcn_mfma_f32_16x16x32_bf16(a, b, c, 0, 0, 0);
}
__device__ __forceinline__ bf16x8 ld8(const u16* p) {
  return *reinterpret_cast<const bf16x8*>(p);
}
// Agent-scope relaxed atomics (sc0+sc1): bypass L1/L2, served at the MALL
// coherence point. Used for ALL cross-WG traffic (hex/qex/flags) -> barriers
// need no cache maintenance (no buffer_wbl2 / buffer_inv anywhere).
__device__ __forceinline__ u64 aload64(const u64* p) {
  return __hip_atomic_load(p, __ATOMIC_RELAXED, __HIP_MEMORY_SCOPE_AGENT);
}
__device__ __forceinline__ void astore64(u64* p, u64 v) {
  __hip_atomic_store(p, v, __ATOMIC_RELAXED, __HIP_MEMORY_SCOPE_AGENT);
}
__device__ __forceinline__ f32x4 fz4() { f32x4 v = {0.f, 0.f, 0.f, 0.f}; return v; }
__device__ __forceinline__ u16 f2b(float f) {           // RNE f32 -> bf16 bits
  unsigned u = __float_as_uint(f);
  unsigned r = (u + 0x7fffu + ((u >> 16) & 1u)) >> 16;
  return (u16)r;
}
__device__ __forceinline__ float b2f(u16 x) { return __uint_as_float(((unsigned)x) << 16); }
__device__ __forceinline__ float sigm(float x) { return 1.f / (1.f + expf(-x)); }

// ---------------- weight / input conversion ----------------
__global__ void k_conv(const float* __restrict__ s, u16* __restrict__ d, int n) {
  int i = blockIdx.x * 256 + threadIdx.x;
  if (i < n) d[i] = f2b(s[i]);
}
// src [K][N] row-major f32  ->  dst[(n+nOff)*ld + kOff + k] bf16  (transposed)
__global__ void k_tconv(const float* __restrict__ s, u16* __restrict__ d,
                        int K, int N, int ld, int nOff, int kOff) {
  int i = blockIdx.x * 256 + threadIdx.x;
  if (i >= K * N) return;
  int k = i / N, n = i - k * N;
  d[(n + nOff) * ld + kOff + k] = f2b(s[i]);
}
__global__ void k_padWg(u16* __restrict__ d) {  // zero Wgt[:, 560:576]
  int i = blockIdx.x * 256 + threadIdx.x;
  if (i >= 1536 * 16) return;
  int n = i >> 4, j = i & 15;
  d[n * GK + 560 + j] = 0;
}
__global__ void k_zeroN(unsigned* p, int n) {
  int i = blockIdx.x * 256 + threadIdx.x;
  if (i < n) p[i] = 0u;
}

// ---------------- 4-WG group barrier (fence-free) ---------------------------
// Group = 4 WGs sharing one 16-row batch shard. Data moved via sc0/sc1 bypass
// (coalesced 8B/lane stores); the explicit vmcnt(0) drain means all stores are
// MALL-acked before the flag posts. Poll is relaxed (no per-poll invalidates).
__device__ __forceinline__ void wbar(unsigned* gf, int j, unsigned tgt) {
  __syncthreads();                                  // WG-wide: everyone's phase done
  asm volatile("s_waitcnt vmcnt(0)" ::: "memory");  // data MALL-acked before flag
  if (threadIdx.x < 64) {
    if (threadIdx.x == 0)
      __hip_atomic_store(gf + j * 32, tgt, __ATOMIC_RELAXED, __HIP_MEMORY_SCOPE_AGENT);
    const int l = threadIdx.x & 3;
    for (;;) {
      unsigned v = __hip_atomic_load(gf + l * 32, __ATOMIC_RELAXED, __HIP_MEMORY_SCOPE_AGENT);
      if (__all((int)(v >= tgt))) break;
      __builtin_amdgcn_s_sleep(1);
    }
  }
  __syncthreads();
}

// ---------------- persistent sequential kernel ------------------------------
// HYBRID DECOMPOSITION: 8 groups x 16 batch rows; 4 WGs per group, each owning
// 128 of the 512 h/q1 columns. Weight stream per WG per step ~690KB from L2
// (4 WGs on one XCD stream the SAME col-slice -> L2-resident). Exchange per
// group per phase = 16KB via hex/qex in [col][row] layout: one contiguous
// 8B sc1 store per lane (vs rounds 0-3's scattered 2B stores whose drain
// dominated the barrier cost). z computed redundantly per WG (no 3rd barrier).
struct SeqArgs {
  const u16* h0b;      // [128][512] bf16
  const u16* z0b;      // [128][32] bf16
  const float* h0;     // [128][512] f32
  const u16* actb;     // [B][T][16]
  const u16* obsb;     // [B][T][256]
  const float* eps;    // [B][T][32]
  const u16* Wgt;      // [1536][576]  (r|u|n gates, K=[h512,z32,a16,pad16])
  const float* bih; const float* bhh;
  const u16* qW1t;     // [512][768]
  const u16* qW2t;     // [64][512]
  const float* qb1; const float* qb2;
  u16* h_all;          // [B*T][512]  cached (heads read after dispatch end)
  u16* z_all;          // [B*T][32]   cached
  u16* hex;            // [8 g][512 c][16 b] bypass exchange
  u16* qex;            // [8 g][512 c][16 b]
  float* out_h; float* out_z; float* out_pomu; float* out_pols;
  unsigned* flags;     // [8 g][4 j][32 pad u32]
};

__global__ __launch_bounds__(512, 1) void k_seq(SeqArgs A) {
  __shared__ u16 h_lds[16][HLP];      // h(t-1) full 512 cols (single buffer:
  __shared__ u16 q_lds[16][HLP];      //  overwrite is barrier-separated from reads)
  __shared__ u16 z_lds[16][40];
  const int tid = threadIdx.x;
  const int lane = tid & 63, wv = tid >> 6, quad = lane >> 4, r16 = lane & 15;
  const int g = blockIdx.x >> 2, j = blockIdx.x & 3;
  const int b0 = g * 16;              // group's 16 batch rows
  const int col0 = j * 128 + wv * 16; // this wave's 16 output cols (1 MFMA tile)
  u16* hex = A.hex + g * (512 * 16);
  u16* qex = A.qex + g * (512 * 16);
  unsigned* gf = A.flags + g * (4 * 32);
  const bf16x8 zf = {(__bf16)0.f,(__bf16)0.f,(__bf16)0.f,(__bf16)0.f,
                     (__bf16)0.f,(__bf16)0.f,(__bf16)0.f,(__bf16)0.f};

  // ---- bootstrap: h0/z0 -> LDS, f32 carry, biases, qW1 slice -> registers ---
  for (int idx = tid; idx < 16 * 64; idx += 512) {
    int r = idx >> 6, c8 = idx & 63;
    *(uint4*)&h_lds[r][c8 * 8] = *(const uint4*)(A.h0b + (b0 + r) * Dn + c8 * 8);
  }
  if (tid < 64) {
    int r = tid >> 2, c8 = tid & 3;
    *(uint4*)&z_lds[r][c8 * 8] = *(const uint4*)(A.z0b + (b0 + r) * Sn + c8 * 8);
  }
  bf16x8 lwreg[24];
#pragma unroll
  for (int kc = 0; kc < 24; ++kc)
    lwreg[kc] = ld8(A.qW1t + (col0 + r16) * 768 + kc * 32 + quad * 8);
  float hcar[4];
#pragma unroll
  for (int i = 0; i < 4; ++i)
    hcar[i] = A.h0[(b0 + quad * 4 + i) * Dn + col0 + r16];
  const int ch = col0 + r16;          // this lane's output column
  const float br_  = A.bih[ch] + A.bhh[ch];
  const float bu_  = A.bih[Dn + ch] + A.bhh[Dn + ch];
  const float bni_ = A.bih[2 * Dn + ch];
  const float bnh_ = A.bhh[2 * Dn + ch];
  const float qb_  = A.qb1[ch];
  float bm_ = 0.f, bl_ = 0.f;
  if (wv < 2) { const int c = wv * 16 + r16; bm_ = A.qb2[c]; bl_ = A.qb2[c + Sn]; }
  const u16* wR  = A.Wgt + (long)ch * GK;
  const u16* wU  = A.Wgt + (long)(512 + ch) * GK;
  const u16* wN  = A.Wgt + (long)(1024 + ch) * GK;
  const u16* w2m = A.qW2t + (wv * 16 + r16) * 512;
  const u16* w2l = A.qW2t + (32 + wv * 16 + r16) * 512;
  __syncthreads();

  unsigned tgt = 0;
  for (int t = 0; t < Tn; ++t) {
    // -------- prefetch pure inputs (cached, fresh addresses) ----------------
    bf16x8 obs_pre[8];
#pragma unroll
    for (int kc = 0; kc < 8; ++kc)
      obs_pre[kc] = ld8(A.obsb + ((b0 + r16) * Tn + t) * Ln + kc * 32 + quad * 8);
    bf16x8 act_pre = zf;
    if (quad < 2) act_pre = ld8(A.actb + ((b0 + r16) * Tn + t) * An + quad * 8);
    float eps_pre[4] = {0.f, 0.f, 0.f, 0.f};
    if (wv < 2) {
#pragma unroll
      for (int i = 0; i < 4; ++i)
        eps_pre[i] = A.eps[((long)(b0 + quad * 4 + i) * Tn + t) * Sn + wv * 16 + r16];
    }

    // ================= phase 1: GRU gates (B streamed from L2) ==============
    f32x4 aR = fz4(), aU = fz4(), aNh = fz4(), aNi = fz4();
#pragma unroll 4
    for (int kc = 0; kc < 16; ++kc) {
      const int k = kc * 32 + quad * 8;
      bf16x8 a0 = ld8(&h_lds[r16][k]);
      aR  = mfma16(a0, ld8(wR + k), aR);
      aU  = mfma16(a0, ld8(wU + k), aU);
      aNh = mfma16(a0, ld8(wN + k), aNh);
    }
    {  // k = 512..543: z columns
      const int k = 512 + quad * 8;
      bf16x8 a0 = ld8(&z_lds[r16][quad * 8]);
      aR  = mfma16(a0, ld8(wR + k), aR);
      aU  = mfma16(a0, ld8(wU + k), aU);
      aNi = mfma16(a0, ld8(wN + k), aNi);
    }
    {  // k = 544..575: action columns (+ zero pad)
      const int k = 544 + quad * 8;
      aR  = mfma16(act_pre, ld8(wR + k), aR);
      aU  = mfma16(act_pre, ld8(wU + k), aU);
      aNi = mfma16(act_pre, ld8(wN + k), aNi);
    }
    {
      u16 hb[4]; float hf[4];
#pragma unroll
      for (int i = 0; i < 4; ++i) {
        const float r = sigm(aR[i] + br_);
        const float u = sigm(aU[i] + bu_);
        const float n = tanhf(aNi[i] + bni_ + r * (aNh[i] + bnh_));
        const float hv = (1.f - u) * n + u * hcar[i];
        hcar[i] = hv; hf[i] = hv; hb[i] = f2b(hv);
      }
      // exchange: [c][b] layout -> ONE contiguous aligned 8B store per lane
      u64 pk = (u64)hb[0] | ((u64)hb[1] << 16) | ((u64)hb[2] << 32) | ((u64)hb[3] << 48);
      astore64((u64*)&hex[ch * 16 + quad * 4], pk);
#pragma unroll
      for (int i = 0; i < 4; ++i) {        // outputs: cached, drain lazily
        const long o = (long)(b0 + quad * 4 + i) * Tn + t;
        A.out_h[o * Dn + ch] = hf[i];
        A.h_all[o * Dn + ch] = hb[i];
      }
    }
    ++tgt; wbar(gf, j, tgt);               // group barrier 1 (4 WGs)
    {  // hex -> h_lds transpose: thread tid owns column c = tid
      const u64* src = (const u64*)(hex + tid * 16);
      u64 v0 = aload64(src), v1 = aload64(src + 1), v2 = aload64(src + 2), v3 = aload64(src + 3);
#pragma unroll
      for (int b = 0; b < 4; ++b) {
        h_lds[b][tid]      = (u16)(v0 >> (16 * b));
        h_lds[4 + b][tid]  = (u16)(v1 >> (16 * b));
        h_lds[8 + b][tid]  = (u16)(v2 >> (16 * b));
        h_lds[12 + b][tid] = (u16)(v3 >> (16 * b));
      }
    }
    __syncthreads();                       // h(t) full tile ready in LDS

    // ================= phase 2: posterior L1 (B in registers) ===============
    f32x4 q = fz4();
#pragma unroll 4
    for (int kc = 0; kc < 16; ++kc) {
      const int k = kc * 32 + quad * 8;
      q = mfma16(ld8(&h_lds[r16][k]), lwreg[kc], q);
    }
#pragma unroll
    for (int kc = 0; kc < 8; ++kc)
      q = mfma16(obs_pre[kc], lwreg[16 + kc], q);
    {
      u16 qv[4];
#pragma unroll
      for (int i = 0; i < 4; ++i) qv[i] = f2b(fmaxf(q[i] + qb_, 0.f));
      u64 pk = (u64)qv[0] | ((u64)qv[1] << 16) | ((u64)qv[2] << 32) | ((u64)qv[3] << 48);
      astore64((u64*)&qex[ch * 16 + quad * 4], pk);
    }
    ++tgt; wbar(gf, j, tgt);               // group barrier 2 (4 WGs)
    {  // qex -> q_lds transpose
      const u64* src = (const u64*)(qex + tid * 16);
      u64 v0 = aload64(src), v1 = aload64(src + 1), v2 = aload64(src + 2), v3 = aload64(src + 3);
#pragma unroll
      for (int b = 0; b < 4; ++b) {
        q_lds[b][tid]      = (u16)(v0 >> (16 * b));
        q_lds[4 + b][tid]  = (u16)(v1 >> (16 * b));
        q_lds[8 + b][tid]  = (u16)(v2 >> (16 * b));
        q_lds[12 + b][tid] = (u16)(v3 >> (16 * b));
      }
    }
    __syncthreads();                       // q1(t) full tile ready in LDS

    // ========== phase 3: posterior L2 + sample (waves 0-1, redundant) =======
    // Inputs (q_lds, qW2, eps) are bitwise identical across the 4 group WGs ->
    // z_lds consistent everywhere; j==0 writes the globals. No 3rd barrier.
    if (wv < 2) {
      f32x4 am = fz4(), al = fz4();
#pragma unroll 4
      for (int kc = 0; kc < 16; ++kc) {
        const int k = kc * 32 + quad * 8;
        bf16x8 a0 = ld8(&q_lds[r16][k]);
        am = mfma16(a0, ld8(w2m + k), am);
        al = mfma16(a0, ld8(w2l + k), al);
      }
      const int c = wv * 16 + r16;
#pragma unroll
      for (int i = 0; i < 4; ++i) {
        const int brow = quad * 4 + i;
        const float mu = am[i] + bm_;
        const float ls = fminf(fmaxf(al[i] + bl_, -10.f), 2.f);
        const float z = mu + eps_pre[i] * expf(ls);
        z_lds[brow][c] = f2b(z);
        if (j == 0) {
          const long o = ((long)(b0 + brow) * Tn + t) * Sn + c;
          A.out_z[o] = z; A.out_pomu[o] = mu; A.out_pols[o] = ls;
          A.z_all[o] = f2b(z);
        }
      }
    }
    __syncthreads();                       // z(t) ready for next step's gates
  }
}

// ---------------- batched prior MLP over all B*T rows ----------------
__global__ __launch_bounds__(256) void k_prior(
    const u16* __restrict__ h_all,
    const u16* __restrict__ pW1t, const float* __restrict__ pb1,
    const u16* __restrict__ pW2t, const float* __restrict__ pb2,
    float* __restrict__ out_pmu, float* __restrict__ out_pls)
{
  __shared__ u16 hid[64 * 512];
  const int tid = threadIdx.x, lane = tid & 63, wv = tid >> 6;
  const int quad = lane >> 4, r16 = lane & 15;
  const int m0 = blockIdx.x * 64;
  f32x4 acc[4][8];
#pragma unroll
  for (int a = 0; a < 4; ++a)
#pragma unroll
    for (int c = 0; c < 8; ++c) acc[a][c] = fz4();
  for (int kc = 0; kc < 16; ++kc) {
    const int k = kc * 32 + quad * 8;
    bf16x8 av[4];
#pragma unroll
    for (int rb = 0; rb < 4; ++rb)
      av[rb] = ld8(h_all + (long)(m0 + rb * 16 + r16) * Dn + k);
#pragma unroll
    for (int cb = 0; cb < 8; ++cb) {
      bf16x8 bb = ld8(pW1t + (wv * 128 + cb * 16 + r16) * Dn + k);
#pragma unroll
      for (int rb = 0; rb < 4; ++rb) acc[rb][cb] = mfma16(av[rb], bb, acc[rb][cb]);
    }
  }
#pragma unroll
  for (int rb = 0; rb < 4; ++rb)
#pragma unroll
    for (int cb = 0; cb < 8; ++cb) {
      const int col = wv * 128 + cb * 16 + r16;
      const float pb = pb1[col];
#pragma unroll
      for (int i = 0; i < 4; ++i) {
        const int row = rb * 16 + quad * 4 + i;
        hid[row * 512 + ((col + row * 8) & 511)] = f2b(fmaxf(acc[rb][cb][i] + pb, 0.f));
      }
    }
  __syncthreads();
  f32x4 acc2[4];
#pragma unroll
  for (int rb = 0; rb < 4; ++rb) acc2[rb] = fz4();
  for (int kc = 0; kc < 16; ++kc) {
    const int k = kc * 32 + quad * 8;
    bf16x8 bb = ld8(pW2t + (wv * 16 + r16) * Dn + k);
#pragma unroll
    for (int rb = 0; rb < 4; ++rb) {
      const int row = rb * 16 + r16;
      bf16x8 aa = ld8(&hid[row * 512 + ((k + row * 8) & 511)]);
      acc2[rb] = mfma16(aa, bb, acc2[rb]);
    }
  }
  const int col = wv * 16 + r16;
#pragma unroll
  for (int rb = 0; rb < 4; ++rb)
#pragma unroll
    for (int i = 0; i < 4; ++i) {
      const int r = m0 + rb * 16 + quad * 4 + i;
      float v = acc2[rb][i] + pb2[col];
      if (col < Sn) out_pmu[r * Sn + col] = v;
      else out_pls[r * Sn + col - Sn] = fminf(fmaxf(v, -10.f), 2.f);
    }
}

// ---------------- batched obs head ----------------
__global__ __launch_bounds__(256) void k_obs(
    const u16* __restrict__ h_all, const u16* __restrict__ z_all,
    const u16* __restrict__ hW1t,
    const float* __restrict__ ob1, const u16* __restrict__ oW2t,
    const float* __restrict__ ob2, float* __restrict__ out_obs)
{
  __shared__ u16 hid[64 * 512];
  const int tid = threadIdx.x, lane = tid & 63, wv = tid >> 6;
  const int quad = lane >> 4, r16 = lane & 15;
  const int m0 = blockIdx.x * 64;
  f32x4 acc[4][8];
#pragma unroll
  for (int a = 0; a < 4; ++a)
#pragma unroll
    for (int c = 0; c < 8; ++c) acc[a][c] = fz4();
  for (int kc = 0; kc < 16; ++kc) {
    const int k = kc * 32 + quad * 8;
    bf16x8 av[4];
#pragma unroll
    for (int rb = 0; rb < 4; ++rb)
      av[rb] = ld8(h_all + (long)(m0 + rb * 16 + r16) * Dn + k);
#pragma unroll
    for (int cb = 0; cb < 8; ++cb) {
      bf16x8 bb = ld8(hW1t + (wv * 128 + cb * 16 + r16) * STLD + k);
#pragma unroll
      for (int rb = 0; rb < 4; ++rb) acc[rb][cb] = mfma16(av[rb], bb, acc[rb][cb]);
    }
  }
  {  // kc == 16: z columns
    const int k = 512 + quad * 8;
    bf16x8 av[4];
#pragma unroll
    for (int rb = 0; rb < 4; ++rb)
      av[rb] = ld8(z_all + (long)(m0 + rb * 16 + r16) * Sn + quad * 8);
#pragma unroll
    for (int cb = 0; cb < 8; ++cb) {
      bf16x8 bb = ld8(hW1t + (wv * 128 + cb * 16 + r16) * STLD + k);
#pragma unroll
      for (int rb = 0; rb < 4; ++rb) acc[rb][cb] = mfma16(av[rb], bb, acc[rb][cb]);
    }
  }
#pragma unroll
  for (int rb = 0; rb < 4; ++rb)
#pragma unroll
    for (int cb = 0; cb < 8; ++cb) {
      const int col = wv * 128 + cb * 16 + r16;
      const float ob = ob1[col];
#pragma unroll
      for (int i = 0; i < 4; ++i) {
        const int row = rb * 16 + quad * 4 + i;
        hid[row * 512 + ((col + row * 8) & 511)] = f2b(fmaxf(acc[rb][cb][i] + ob, 0.f));
      }
    }
  __syncthreads();
  f32x4 acc2[4][4];
#pragma unroll
  for (int a = 0; a < 4; ++a)
#pragma unroll
    for (int c = 0; c < 4; ++c) acc2[a][c] = fz4();
  for (int kc = 0; kc < 16; ++kc) {
    const int k = kc * 32 + quad * 8;
    bf16x8 aa[4];
#pragma unroll
    for (int rb = 0; rb < 4; ++rb) {
      const int row = rb * 16 + r16;
      aa[rb] = ld8(&hid[row * 512 + ((k + row * 8) & 511)]);
    }
#pragma unroll
    for (int cb = 0; cb < 4; ++cb) {
      bf16x8 bb = ld8(oW2t + (wv * 64 + cb * 16 + r16) * Dn + k);
#pragma unroll
      for (int rb = 0; rb < 4; ++rb) acc2[rb][cb] = mfma16(aa[rb], bb, acc2[rb][cb]);
    }
  }
#pragma unroll
  for (int rb = 0; rb < 4; ++rb)
#pragma unroll
    for (int cb = 0; cb < 4; ++cb) {
      const int col = wv * 64 + cb * 16 + r16;
      const float ob = ob2[col];
#pragma unroll
      for (int i = 0; i < 4; ++i) {
        const int r = m0 + rb * 16 + quad * 4 + i;
        out_obs[r * Ln + col] = acc2[rb][cb][i] + ob;
      }
    }
}

// ---------------- batched reward + done heads ----------------
__global__ __launch_bounds__(256) void k_rewdone(
    const u16* __restrict__ h_all, const u16* __restrict__ z_all,
    const u16* __restrict__ hW1t,
    const float* __restrict__ rb1, const float* __restrict__ rW2, const float* __restrict__ rb2,
    const float* __restrict__ db1, const float* __restrict__ dW2, const float* __restrict__ db2,
    float* __restrict__ out_rew, float* __restrict__ out_done)
{
  __shared__ u16 hid[64 * 512];
  const int tid = threadIdx.x, lane = tid & 63, wv = tid >> 6;
  const int quad = lane >> 4, r16 = lane & 15;
  const int m0 = blockIdx.x * 64;

  for (int head = 0; head < 2; ++head) {
    const float* b1 = head ? db1 : rb1;
    const float* w2 = head ? dW2 : rW2;
    float* outp = head ? out_done : out_rew;
    const int nb = 512 + head * 512;

    f32x4 acc[4][8];
#pragma unroll
    for (int a = 0; a < 4; ++a)
#pragma unroll
      for (int c = 0; c < 8; ++c) acc[a][c] = fz4();
    for (int kc = 0; kc < 16; ++kc) {
      const int k = kc * 32 + quad * 8;
      bf16x8 av[4];
#pragma unroll
      for (int rb = 0; rb < 4; ++rb)
        av[rb] = ld8(h_all + (long)(m0 + rb * 16 + r16) * Dn + k);
#pragma unroll
      for (int cb = 0; cb < 8; ++cb) {
        bf16x8 bb = ld8(hW1t + (nb + wv * 128 + cb * 16 + r16) * STLD + k);
#pragma unroll
        for (int rb = 0; rb < 4; ++rb) acc[rb][cb] = mfma16(av[rb], bb, acc[rb][cb]);
      }
    }
    {  // kc == 16: z columns
      const int k = 512 + quad * 8;
      bf16x8 av[4];
#pragma unroll
      for (int rb = 0; rb < 4; ++rb)
        av[rb] = ld8(z_all + (long)(m0 + rb * 16 + r16) * Sn + quad * 8);
#pragma unroll
      for (int cb = 0; cb < 8; ++cb) {
        bf16x8 bb = ld8(hW1t + (nb + wv * 128 + cb * 16 + r16) * STLD + k);
#pragma unroll
        for (int rb = 0; rb < 4; ++rb) acc[rb][cb] = mfma16(av[rb], bb, acc[rb][cb]);
      }
    }
#pragma unroll
    for (int rb = 0; rb < 4; ++rb)
#pragma unroll
      for (int cb = 0; cb < 8; ++cb) {
        const int col = wv * 128 + cb * 16 + r16;
        const float bv = b1[col];
#pragma unroll
        for (int i = 0; i < 4; ++i) {
          const int row = rb * 16 + quad * 4 + i;
          hid[row * 512 + ((col + row * 8) & 511)] = f2b(fmaxf(acc[rb][cb][i] + bv, 0.f));
        }
      }
    __syncthreads();
    const int row = tid >> 2, part = tid & 3;
    float s = 0.f;
    for (int c = part * 128; c < part * 128 + 128; ++c)
      s += b2f(hid[row * 512 + ((c + row * 8) & 511)]) * w2[c];
    s += __shfl_xor(s, 1);
    s += __shfl_xor(s, 2);
    if (part == 0) outp[m0 + row] = s + (head ? db2[0] : rb2[0]);
    __syncthreads();
  }
}

// ---------------- host ----------------
extern "C" void kernel_launch(void* const* d_in, const int* in_sizes, int n_in,
                              void* d_out, int out_size, void* d_ws, size_t ws_size,
                              hipStream_t stream) {
  const float* actions = (const float*)d_in[0];
  const float* obs     = (const float*)d_in[1];
  const float* eps     = (const float*)d_in[2];
  const float* h0      = (const float*)d_in[3];
  const float* z0      = (const float*)d_in[4];
  const float* Wih     = (const float*)d_in[5];
  const float* Whh     = (const float*)d_in[6];
  const float* bih     = (const float*)d_in[7];
  const float* bhh     = (const float*)d_in[8];
  const float* pW1     = (const float*)d_in[9];
  const float* pb1     = (const float*)d_in[10];
  const float* pW2     = (const float*)d_in[11];
  const float* pb2     = (const float*)d_in[12];
  const float* qW1     = (const float*)d_in[13];
  const float* qb1     = (const float*)d_in[14];
  const float* qW2     = (const float*)d_in[15];
  const float* qb2     = (const float*)d_in[16];
  const float* oW1     = (const float*)d_in[17];
  const float* ob1     = (const float*)d_in[18];
  const float* oW2     = (const float*)d_in[19];
  const float* ob2     = (const float*)d_in[20];
  const float* rW1     = (const float*)d_in[21];
  const float* rb1     = (const float*)d_in[22];
  const float* rW2     = (const float*)d_in[23];
  const float* rb2     = (const float*)d_in[24];
  const float* dW1     = (const float*)d_in[25];
  const float* db1     = (const float*)d_in[26];
  const float* dW2     = (const float*)d_in[27];
  const float* db2     = (const float*)d_in[28];

  float* out = (float*)d_out;
  float* out_h    = out;                  // [B,T,512]
  float* out_z    = out + 16777216;       // [B,T,32]
  float* out_obs  = out + 17825792;       // [B,T,256]
  float* out_rew  = out + 26214400;       // [B,T]
  float* out_done = out + 26247168;       // [B,T]
  float* out_prmu = out + 26279936;       // [B,T,32]
  float* out_prls = out + 27328512;       // [B,T,32]
  float* out_pomu = out + 28377088;       // [B,T,32]
  float* out_pols = out + 29425664;       // [B,T,32]

  char* w = (char*)d_ws;
  u16* WGT  = (u16*)(w + 0);          // [1536][576]
  u16* QW1T = (u16*)(w + 1769472);    // [512][768]
  u16* QW2T = (u16*)(w + 2555904);    // [64][512]
  u16* PW1T = (u16*)(w + 2621440);    // [512][512]
  u16* PW2T = (u16*)(w + 3145728);    // [64][512]
  u16* HW1T = (u16*)(w + 3211264);    // [1536][544] (obs|rew|done)
  u16* OW2T = (u16*)(w + 4882432);    // [256][512]
  u16* H0B  = (u16*)(w + 5144576);    // [128][512]
  u16* ACTB = (u16*)(w + 5275648);    // [B][T][16]
  u16* OBSB = (u16*)(w + 6324224);    // [B][T][256]
  u16* HALL = (u16*)(w + 23101440);   // [B*T][512]
  u16* ZALL = (u16*)(w + 56655872);   // [B*T][32]
  u16* HEX  = (u16*)(w + 58753024);   // [8][512][16] = 128KB
  u16* Z0B  = (u16*)(w + 58884096);   // [128][32]
  unsigned* FLAGS = (unsigned*)(w + 58892288);  // [8][4][32] u32 = 4KB
  u16* QEX  = (u16*)(w + 58896384);   // [8][512][16] = 128KB -> ends 59,027,456

  auto nb = [](int n) { return dim3((unsigned)((n + 255) / 256)); };

  k_zeroN<<<nb(1024), 256, 0, stream>>>(FLAGS, 1024);
  k_conv<<<nb(128 * 512), 256, 0, stream>>>(h0, H0B, 128 * 512);
  k_conv<<<nb(128 * 32), 256, 0, stream>>>(z0, Z0B, 128 * 32);
  k_conv<<<nb(128 * 256 * 16), 256, 0, stream>>>(actions, ACTB, 128 * 256 * 16);
  k_conv<<<nb(128 * 256 * 256), 256, 0, stream>>>(obs, OBSB, 128 * 256 * 256);
  k_tconv<<<nb(512 * 1536), 256, 0, stream>>>(Whh, WGT, 512, 1536, GK, 0, 0);
  k_tconv<<<nb(48 * 1536), 256, 0, stream>>>(Wih, WGT, 48, 1536, GK, 0, 512);
  k_padWg<<<nb(1536 * 16), 256, 0, stream>>>(WGT);
  k_tconv<<<nb(768 * 512), 256, 0, stream>>>(qW1, QW1T, 768, 512, 768, 0, 0);
  k_tconv<<<nb(512 * 64), 256, 0, stream>>>(qW2, QW2T, 512, 64, 512, 0, 0);
  k_tconv<<<nb(512 * 512), 256, 0, stream>>>(pW1, PW1T, 512, 512, 512, 0, 0);
  k_tconv<<<nb(512 * 64), 256, 0, stream>>>(pW2, PW2T, 512, 64, 512, 0, 0);
  k_tconv<<<nb(544 * 512), 256, 0, stream>>>(oW1, HW1T, 544, 512, STLD, 0, 0);
  k_tconv<<<nb(544 * 512), 256, 0, stream>>>(rW1, HW1T, 544, 512, STLD, 512, 0);
  k_tconv<<<nb(544 * 512), 256, 0, stream>>>(dW1, HW1T, 544, 512, STLD, 1024, 0);
  k_tconv<<<nb(512 * 256), 256, 0, stream>>>(oW2, OW2T, 512, 256, 512, 0, 0);

  SeqArgs sa;
  sa.h0b = H0B; sa.z0b = Z0B; sa.h0 = h0;
  sa.actb = ACTB; sa.obsb = OBSB; sa.eps = eps;
  sa.Wgt = WGT; sa.bih = bih; sa.bhh = bhh;
  sa.qW1t = QW1T; sa.qW2t = QW2T; sa.qb1 = qb1; sa.qb2 = qb2;
  sa.h_all = HALL; sa.z_all = ZALL; sa.hex = HEX; sa.qex = QEX;
  sa.out_h = out_h; sa.out_z = out_z; sa.out_pomu = out_pomu; sa.out_pols = out_pols;
  sa.flags = FLAGS;
  k_seq<<<dim3(32), dim3(512), 0, stream>>>(sa);

  k_prior<<<512, 256, 0, stream>>>(HALL, PW1T, pb1, PW2T, pb2, out_prmu, out_prls);
  k_obs<<<512, 256, 0, stream>>>(HALL, ZALL, HW1T, ob1, OW2T, ob2, out_obs);
  k_rewdone<<<512, 256, 0, stream>>>(HALL, ZALL, HW1T, rb1, rW2, rb2, db1, dW2, db2,
                                     out_rew, out_done);
}

// Round 7
// 3849.714 us; speedup vs baseline: 1.7802x; 1.7802x over previous
//
#include <hip/hip_runtime.h>

// ---------------- problem constants ----------------
constexpr int Bn = 128, Tn = 256, An = 16, Ln = 256, Sn = 32, Dn = 512, Hn = 512;
constexpr int STLD = 544;         // st row = [h(512), z(32)]
constexpr int GK   = 576;         // gates K padded: [h 512, z 32, a 16, pad 16]
constexpr int GRID = 64;          // persistent WGs (<= 256 CUs -> always co-resident)
constexpr int GWP  = 584;         // LDS gw row stride (conflict-free padding)

typedef __bf16 bf16x8 __attribute__((ext_vector_type(8)));
typedef float  f32x4  __attribute__((ext_vector_type(4)));
typedef unsigned short u16;
typedef unsigned long long u64;

__device__ __forceinline__ f32x4 mfma16(bf16x8 a, bf16x8 b, f32x4 c) {
  return __builtin_amdgcn_mfma_f32_16x16x32_bf16(a, b, c, 0, 0, 0);
}
__device__ __forceinline__ bf16x8 ld8(const u16* p) {
  return *reinterpret_cast<const bf16x8*>(p);
}
// Agent-scope relaxed (sc0+sc1) bypass accesses: serve at the MALL coherence
// point. Used for cross-WG data (st_all h/z, q1) and barrier flags.
__device__ __forceinline__ bf16x8 ld8c(const u16* p) {
  union { u64 q[2]; bf16x8 v; } u;
  u.q[0] = __hip_atomic_load((const u64*)p,       __ATOMIC_RELAXED, __HIP_MEMORY_SCOPE_AGENT);
  u.q[1] = __hip_atomic_load((const u64*)(p + 4), __ATOMIC_RELAXED, __HIP_MEMORY_SCOPE_AGENT);
  return u.v;
}
__device__ __forceinline__ void st2c(u16* p, u16 v) {
  __hip_atomic_store(p, v, __ATOMIC_RELAXED, __HIP_MEMORY_SCOPE_AGENT);
}
__device__ __forceinline__ f32x4 fz4() { f32x4 v = {0.f, 0.f, 0.f, 0.f}; return v; }
__device__ __forceinline__ u16 f2b(float f) {           // RNE f32 -> bf16 bits
  unsigned u = __float_as_uint(f);
  unsigned r = (u + 0x7fffu + ((u >> 16) & 1u)) >> 16;
  return (u16)r;
}
__device__ __forceinline__ float b2f(u16 x) { return __uint_as_float(((unsigned)x) << 16); }
__device__ __forceinline__ float sigm(float x) { return 1.f / (1.f + expf(-x)); }

// ---------------- weight / input conversion ----------------
__global__ void k_conv(const float* __restrict__ s, u16* __restrict__ d, int n) {
  int i = blockIdx.x * 256 + threadIdx.x;
  if (i < n) d[i] = f2b(s[i]);
}
// src [K][N] row-major f32  ->  dst[(n+nOff)*ld + kOff + k] bf16  (transposed)
__global__ void k_tconv(const float* __restrict__ s, u16* __restrict__ d,
                        int K, int N, int ld, int nOff, int kOff) {
  int i = blockIdx.x * 256 + threadIdx.x;
  if (i >= K * N) return;
  int k = i / N, n = i - k * N;
  d[(n + nOff) * ld + kOff + k] = f2b(s[i]);
}
__global__ void k_padWg(u16* __restrict__ d) {  // zero Wgt[:, 560:576]
  int i = blockIdx.x * 256 + threadIdx.x;
  if (i >= 1536 * 16) return;
  int n = i >> 4, j = i & 15;
  d[n * GK + 560 + j] = 0;
}
__global__ void k_zeroN(unsigned* p, int n) {
  int i = blockIdx.x * 256 + threadIdx.x;
  if (i < n) p[i] = 0u;
}

// ------- split barrier: thin drain + deferred-store window + parallel poll ---
// Two independent 32-WG domains (row-halves never exchange data). gbar_flag:
// per-wave vmcnt drain (ONLY the exchange st2c's issued so far; output stores
// are issued AFTER the flag and retire during the poll -> their L2
// write-allocate RFO latency leaves the critical chain), syncthreads, post
// per-WG flag. gbar_wait: 32 lanes poll 32 flags in one parallel relaxed
// agent load. No acquire/release fences anywhere (all cross-WG data is sc1).
__device__ __forceinline__ void gbar_flag(unsigned* gflags, int idx, unsigned tgt) {
  asm volatile("s_waitcnt vmcnt(0) lgkmcnt(0)" ::: "memory");
  __syncthreads();
  if (threadIdx.x == 0)
    __hip_atomic_store(gflags + idx * 32, tgt, __ATOMIC_RELAXED, __HIP_MEMORY_SCOPE_AGENT);
}
__device__ __forceinline__ void gbar_wait(unsigned* gflags, unsigned tgt) {
  if (threadIdx.x < 64) {
    const int l = threadIdx.x & 31;
    for (;;) {
      unsigned v = __hip_atomic_load(gflags + l * 32, __ATOMIC_RELAXED, __HIP_MEMORY_SCOPE_AGENT);
      if (__all((int)(v >= tgt))) break;
      __builtin_amdgcn_s_sleep(1);
    }
  }
  __syncthreads();
}

// ---------------- persistent sequential kernel ----------------
struct SeqArgs {
  const u16* h0b;      // [128][512] bf16
  const u16* z0b;      // [128][32] bf16
  const float* h0;     // [128][512] f32
  const u16* actb;     // [B][T][16]
  const u16* obsb;     // [B][T][256]
  const float* eps;    // [B][T][32]
  const u16* Wgt;      // [1536][576]
  const float* bih; const float* bhh;
  const u16* qW1t;     // [512][768]
  const u16* qW2t;     // [64][512]
  const float* qb1; const float* qb2;
  u16* st_all;         // [B*T][544]
  u16* q1;             // [128][512]
  float* out_h; float* out_z; float* out_pomu; float* out_pols;
  unsigned* flags;     // [2 halves][32 wg][32 u32 pad]
};

__global__ __launch_bounds__(256, 1) void k_seq(SeqArgs A) {
  __shared__ u16 gw[48 * GWP];
  const int tid = threadIdx.x, w = blockIdx.x;
  const int lane = tid & 63, wv = tid >> 6, quad = lane >> 4, r16 = lane & 15;
  const int wq = w & 31;                // index within half
  const int cslice = wq * 16;           // 16-col slice (GRU h-cols & L1 cols)
  const int mh = w >> 5;                // M-half (independent barrier domain)
  const int mrow0 = mh * 64 + wv * 16;  // this wave's 16 A-rows
  unsigned* gflags = A.flags + mh * 32 * 32;
  // phase-C workers: 8 per half (4 row-blocks x 2 col-tiles), wave 0 only.
  // NOTE: each half owns rows [mh*64, mh*64+64) ONLY -> wq<8, wq>>1 in 0..3.
  const bool cwave = (wq < 8) && (wv == 0);
  const int mrowC = mh * 64 + (wq >> 1) * 16;  // C row-block (within own half)
  const int ntm = wq & 1;                      // C col-tile (mu/ls 16-col pair)
  const bf16x8 z8 = {(__bf16)0.f,(__bf16)0.f,(__bf16)0.f,(__bf16)0.f,
                     (__bf16)0.f,(__bf16)0.f,(__bf16)0.f,(__bf16)0.f};

  // stage GRU weight slice into LDS: rows {r,u,n}x16cols, K=576 (pad to 584)
  for (int idx = tid; idx < 48 * 72; idx += 256) {
    int r = idx / 72, c = idx - r * 72;
    int g = r >> 4, rr = r & 15;
    const u16* src = A.Wgt + (g * 512 + cslice + rr) * GK + c * 8;
    *(uint4*)&gw[r * GWP + c * 8] = *(const uint4*)src;
  }
  // L1 weight frags -> registers (reused all 256 steps)
  bf16x8 lwreg[24];
#pragma unroll
  for (int kc = 0; kc < 24; ++kc)
    lwreg[kc] = ld8(A.qW1t + (cslice + r16) * 768 + kc * 32 + quad * 8);
  // carried h (f32) for this lane's 4 (row,col) cells
  float hcar[4];
#pragma unroll
  for (int i = 0; i < 4; ++i)
    hcar[i] = A.h0[(mh * 64 + wv * 16 + quad * 4 + i) * Dn + cslice + r16];
  // h A-fragments live in registers: phase B(t) reloads them from st_all(t),
  // phase A(t+1) consumes them again (identical bf16 values -> no reload).
  bf16x8 a_h[16];
#pragma unroll
  for (int kc = 0; kc < 16; ++kc)
    a_h[kc] = ld8(A.h0b + (mrow0 + r16) * Dn + kc * 32 + quad * 8);
  __syncthreads();

  unsigned tgt = 0;
  for (int t = 0; t < Tn; ++t) {
    // -------- step-top prefetches (latency hidden under phase A) ------------
    bf16x8 obs_pre[8];
#pragma unroll
    for (int kc = 0; kc < 8; ++kc)
      obs_pre[kc] = ld8(A.obsb + ((mrow0 + r16) * Tn + t) * Ln + kc * 32 + quad * 8);
    bf16x8 act_pre = z8;
    if (quad < 2) act_pre = ld8(A.actb + ((mrow0 + r16) * Tn + t) * An + quad * 8);
    bf16x8 zfrag;
    if (t == 0) zfrag = ld8(A.z0b + (mrow0 + r16) * Sn + quad * 8);
    else        zfrag = ld8c(A.st_all + ((long)(mrow0 + r16) * Tn + (t - 1)) * STLD
                             + Dn + quad * 8);
    float eps_pre[4] = {0.f, 0.f, 0.f, 0.f};
    if (cwave) {
#pragma unroll
      for (int i = 0; i < 4; ++i)
        eps_pre[i] = A.eps[((long)(mrowC + quad * 4 + i) * Tn + t) * Sn + ntm * 16 + r16];
    }

    // ================= phase A: GRU (register A-operands, LDS weights) ======
    f32x4 aR = fz4(), aU = fz4(), aNi = fz4(), aNh = fz4();
#pragma unroll
    for (int kc = 0; kc < 16; ++kc) {
      const int k = kc * 32 + quad * 8;
      bf16x8 bR = ld8(&gw[r16 * GWP + k]);
      bf16x8 bU = ld8(&gw[(16 + r16) * GWP + k]);
      bf16x8 bN = ld8(&gw[(32 + r16) * GWP + k]);
      aR = mfma16(a_h[kc], bR, aR);
      aU = mfma16(a_h[kc], bU, aU);
      aNh = mfma16(a_h[kc], bN, aNh);
    }
    {  // kc == 16: z columns
      const int k = 512 + quad * 8;
      aR = mfma16(zfrag, ld8(&gw[r16 * GWP + k]), aR);
      aU = mfma16(zfrag, ld8(&gw[(16 + r16) * GWP + k]), aU);
      aNi = mfma16(zfrag, ld8(&gw[(32 + r16) * GWP + k]), aNi);
    }
    {  // kc == 17: action columns (+pad)
      const int k = 544 + quad * 8;
      aR = mfma16(act_pre, ld8(&gw[r16 * GWP + k]), aR);
      aU = mfma16(act_pre, ld8(&gw[(16 + r16) * GWP + k]), aU);
      aNi = mfma16(act_pre, ld8(&gw[(32 + r16) * GWP + k]), aNi);
    }
    float hvf[4];
    {
      const int ch = cslice + r16;
      const float br  = A.bih[ch] + A.bhh[ch];
      const float bu  = A.bih[Dn + ch] + A.bhh[Dn + ch];
      const float bni = A.bih[2 * Dn + ch];
      const float bnh = A.bhh[2 * Dn + ch];
#pragma unroll
      for (int i = 0; i < 4; ++i) {
        const int b = mh * 64 + wv * 16 + quad * 4 + i;
        const float r = sigm(aR[i] + br);
        const float u = sigm(aU[i] + bu);
        const float n = tanhf(aNi[i] + bni + r * (aNh[i] + bnh));
        const float hv = (1.f - u) * n + u * hcar[i];
        hcar[i] = hv; hvf[i] = hv;
        st2c(&A.st_all[((long)b * Tn + t) * STLD + ch], f2b(hv));  // exchange
      }
    }
    ++tgt; gbar_flag(gflags, wq, tgt);   // drain exchange only, post flag
    {  // deferred output stores: retire during the poll (RFO off the chain)
      const int ch = cslice + r16;
#pragma unroll
      for (int i = 0; i < 4; ++i) {
        const int b = mh * 64 + wv * 16 + quad * 4 + i;
        A.out_h[((long)b * Tn + t) * Dn + ch] = hvf[i];
      }
    }
    gbar_wait(gflags, tgt);              // barrier 1

    // ================= phase B: posterior L1 ================================
    // Issue the full h-gather first (one MALL latency covers all 16), do the
    // obs MFMAs (operands already in regs) while loads fly, then h MFMAs.
    // a_h reload doubles as the GRU A-operand for step t+1.
#pragma unroll
    for (int kc = 0; kc < 16; ++kc)
      a_h[kc] = ld8(A.st_all + ((long)(mrow0 + r16) * Tn + t) * STLD + kc * 32 + quad * 8);
    f32x4 q = fz4();
#pragma unroll
    for (int kc = 0; kc < 8; ++kc)
      q = mfma16(obs_pre[kc], lwreg[16 + kc], q);
#pragma unroll
    for (int kc = 0; kc < 16; ++kc)
      q = mfma16(a_h[kc], lwreg[kc], q);
    {
      const int col = cslice + r16;
      const float qb = A.qb1[col];
#pragma unroll
      for (int i = 0; i < 4; ++i) {
        const int b = mh * 64 + wv * 16 + quad * 4 + i;
        st2c(&A.q1[b * Hn + col], f2b(fmaxf(q[i] + qb, 0.f)));  // exchange
      }
    }
    ++tgt; gbar_flag(gflags, wq, tgt);
    gbar_wait(gflags, tgt);              // barrier 2

    // ================= phase C: posterior L2 + sample (8 waves/half) ========
    float muv[4], lsv[4], zv[4];
    if (cwave) {
      bf16x8 qa[16];
#pragma unroll
      for (int kc = 0; kc < 16; ++kc)    // full q1 gather issued up front
        qa[kc] = ld8c(A.q1 + (mrowC + r16) * Hn + kc * 32 + quad * 8);
      f32x4 am = fz4(), al = fz4();
#pragma unroll
      for (int kc = 0; kc < 16; ++kc) {
        const int k = kc * 32 + quad * 8;
        am = mfma16(qa[kc], ld8(A.qW2t + (ntm * 16 + r16) * 512 + k), am);
        al = mfma16(qa[kc], ld8(A.qW2t + (ntm * 16 + 32 + r16) * 512 + k), al);
      }
      const int col = ntm * 16 + r16;
      const float bm = A.qb2[col], bl = A.qb2[col + Sn];
#pragma unroll
      for (int i = 0; i < 4; ++i) {
        const int b = mrowC + quad * 4 + i;
        muv[i] = am[i] + bm;
        lsv[i] = fminf(fmaxf(al[i] + bl, -10.f), 2.f);
        zv[i]  = muv[i] + eps_pre[i] * expf(lsv[i]);
        st2c(&A.st_all[((long)b * Tn + t) * STLD + Dn + col], f2b(zv[i])); // exchange
      }
    }
    ++tgt; gbar_flag(gflags, wq, tgt);
    if (cwave) {  // deferred z/mu/ls outputs
      const int col = ntm * 16 + r16;
#pragma unroll
      for (int i = 0; i < 4; ++i) {
        const long o = ((long)(mrowC + quad * 4 + i) * Tn + t) * Sn + col;
        A.out_z[o] = zv[i]; A.out_pomu[o] = muv[i]; A.out_pols[o] = lsv[i];
      }
    }
    gbar_wait(gflags, tgt);              // barrier 3
  }
}

// ---------------- batched prior MLP over all B*T rows ----------------
__global__ __launch_bounds__(256) void k_prior(
    const u16* __restrict__ st_all,
    const u16* __restrict__ pW1t, const float* __restrict__ pb1,
    const u16* __restrict__ pW2t, const float* __restrict__ pb2,
    float* __restrict__ out_pmu, float* __restrict__ out_pls)
{
  __shared__ u16 hid[64 * 512];
  const int tid = threadIdx.x, lane = tid & 63, wv = tid >> 6;
  const int quad = lane >> 4, r16 = lane & 15;
  const int m0 = blockIdx.x * 64;
  f32x4 acc[4][8];
#pragma unroll
  for (int a = 0; a < 4; ++a)
#pragma unroll
    for (int c = 0; c < 8; ++c) acc[a][c] = fz4();
  for (int kc = 0; kc < 16; ++kc) {
    const int k = kc * 32 + quad * 8;
    bf16x8 av[4];
#pragma unroll
    for (int rb = 0; rb < 4; ++rb)
      av[rb] = ld8(st_all + (long)(m0 + rb * 16 + r16) * STLD + k);
#pragma unroll
    for (int cb = 0; cb < 8; ++cb) {
      bf16x8 bb = ld8(pW1t + (wv * 128 + cb * 16 + r16) * Dn + k);
#pragma unroll
      for (int rb = 0; rb < 4; ++rb) acc[rb][cb] = mfma16(av[rb], bb, acc[rb][cb]);
    }
  }
#pragma unroll
  for (int rb = 0; rb < 4; ++rb)
#pragma unroll
    for (int cb = 0; cb < 8; ++cb) {
      const int col = wv * 128 + cb * 16 + r16;
      const float pb = pb1[col];
#pragma unroll
      for (int i = 0; i < 4; ++i) {
        const int row = rb * 16 + quad * 4 + i;
        hid[row * 512 + ((col + row * 8) & 511)] = f2b(fmaxf(acc[rb][cb][i] + pb, 0.f));
      }
    }
  __syncthreads();
  f32x4 acc2[4];
#pragma unroll
  for (int rb = 0; rb < 4; ++rb) acc2[rb] = fz4();
  for (int kc = 0; kc < 16; ++kc) {
    const int k = kc * 32 + quad * 8;
    bf16x8 bb = ld8(pW2t + (wv * 16 + r16) * Dn + k);
#pragma unroll
    for (int rb = 0; rb < 4; ++rb) {
      const int row = rb * 16 + r16;
      bf16x8 aa = ld8(&hid[row * 512 + ((k + row * 8) & 511)]);
      acc2[rb] = mfma16(aa, bb, acc2[rb]);
    }
  }
  const int col = wv * 16 + r16;
#pragma unroll
  for (int rb = 0; rb < 4; ++rb)
#pragma unroll
    for (int i = 0; i < 4; ++i) {
      const int r = m0 + rb * 16 + quad * 4 + i;
      float v = acc2[rb][i] + pb2[col];
      if (col < Sn) out_pmu[r * Sn + col] = v;
      else out_pls[r * Sn + col - Sn] = fminf(fmaxf(v, -10.f), 2.f);
    }
}

// ---------------- batched obs head ----------------
__global__ __launch_bounds__(256) void k_obs(
    const u16* __restrict__ st_all, const u16* __restrict__ hW1t,
    const float* __restrict__ ob1, const u16* __restrict__ oW2t,
    const float* __restrict__ ob2, float* __restrict__ out_obs)
{
  __shared__ u16 hid[64 * 512];
  const int tid = threadIdx.x, lane = tid & 63, wv = tid >> 6;
  const int quad = lane >> 4, r16 = lane & 15;
  const int m0 = blockIdx.x * 64;
  f32x4 acc[4][8];
#pragma unroll
  for (int a = 0; a < 4; ++a)
#pragma unroll
    for (int c = 0; c < 8; ++c) acc[a][c] = fz4();
  for (int kc = 0; kc < 17; ++kc) {
    const int k = kc * 32 + quad * 8;
    bf16x8 av[4];
#pragma unroll
    for (int rb = 0; rb < 4; ++rb)
      av[rb] = ld8(st_all + (long)(m0 + rb * 16 + r16) * STLD + k);
#pragma unroll
    for (int cb = 0; cb < 8; ++cb) {
      bf16x8 bb = ld8(hW1t + (wv * 128 + cb * 16 + r16) * STLD + k);
#pragma unroll
      for (int rb = 0; rb < 4; ++rb) acc[rb][cb] = mfma16(av[rb], bb, acc[rb][cb]);
    }
  }
#pragma unroll
  for (int rb = 0; rb < 4; ++rb)
#pragma unroll
    for (int cb = 0; cb < 8; ++cb) {
      const int col = wv * 128 + cb * 16 + r16;
      const float ob = ob1[col];
#pragma unroll
      for (int i = 0; i < 4; ++i) {
        const int row = rb * 16 + quad * 4 + i;
        hid[row * 512 + ((col + row * 8) & 511)] = f2b(fmaxf(acc[rb][cb][i] + ob, 0.f));
      }
    }
  __syncthreads();
  f32x4 acc2[4][4];
#pragma unroll
  for (int a = 0; a < 4; ++a)
#pragma unroll
    for (int c = 0; c < 4; ++c) acc2[a][c] = fz4();
  for (int kc = 0; kc < 16; ++kc) {
    const int k = kc * 32 + quad * 8;
    bf16x8 aa[4];
#pragma unroll
    for (int rb = 0; rb < 4; ++rb) {
      const int row = rb * 16 + r16;
      aa[rb] = ld8(&hid[row * 512 + ((k + row * 8) & 511)]);
    }
#pragma unroll
    for (int cb = 0; cb < 4; ++cb) {
      bf16x8 bb = ld8(oW2t + (wv * 64 + cb * 16 + r16) * Dn + k);
#pragma unroll
      for (int rb = 0; rb < 4; ++rb) acc2[rb][cb] = mfma16(aa[rb], bb, acc2[rb][cb]);
    }
  }
#pragma unroll
  for (int rb = 0; rb < 4; ++rb)
#pragma unroll
    for (int cb = 0; cb < 4; ++cb) {
      const int col = wv * 64 + cb * 16 + r16;
      const float ob = ob2[col];
#pragma unroll
      for (int i = 0; i < 4; ++i) {
        const int r = m0 + rb * 16 + quad * 4 + i;
        out_obs[r * Ln + col] = acc2[rb][cb][i] + ob;
      }
    }
}

// ---------------- batched reward + done heads ----------------
__global__ __launch_bounds__(256) void k_rewdone(
    const u16* __restrict__ st_all, const u16* __restrict__ hW1t,
    const float* __restrict__ rb1, const float* __restrict__ rW2, const float* __restrict__ rb2,
    const float* __restrict__ db1, const float* __restrict__ dW2, const float* __restrict__ db2,
    float* __restrict__ out_rew, float* __restrict__ out_done)
{
  __shared__ u16 hid[64 * 512];
  const int tid = threadIdx.x, lane = tid & 63, wv = tid >> 6;
  const int quad = lane >> 4, r16 = lane & 15;
  const int m0 = blockIdx.x * 64;

  for (int head = 0; head < 2; ++head) {
    const float* b1 = head ? db1 : rb1;
    const float* w2 = head ? dW2 : rW2;
    float* outp = head ? out_done : out_rew;
    const int nb = 512 + head * 512;

    f32x4 acc[4][8];
#pragma unroll
    for (int a = 0; a < 4; ++a)
#pragma unroll
      for (int c = 0; c < 8; ++c) acc[a][c] = fz4();
    for (int kc = 0; kc < 17; ++kc) {
      const int k = kc * 32 + quad * 8;
      bf16x8 av[4];
#pragma unroll
      for (int rb = 0; rb < 4; ++rb)
        av[rb] = ld8(st_all + (long)(m0 + rb * 16 + r16) * STLD + k);
#pragma unroll
      for (int cb = 0; cb < 8; ++cb) {
        bf16x8 bb = ld8(hW1t + (nb + wv * 128 + cb * 16 + r16) * STLD + k);
#pragma unroll
        for (int rb = 0; rb < 4; ++rb) acc[rb][cb] = mfma16(av[rb], bb, acc[rb][cb]);
      }
    }
#pragma unroll
    for (int rb = 0; rb < 4; ++rb)
#pragma unroll
      for (int cb = 0; cb < 8; ++cb) {
        const int col = wv * 128 + cb * 16 + r16;
        const float bv = b1[col];
#pragma unroll
        for (int i = 0; i < 4; ++i) {
          const int row = rb * 16 + quad * 4 + i;
          hid[row * 512 + ((col + row * 8) & 511)] = f2b(fmaxf(acc[rb][cb][i] + bv, 0.f));
        }
      }
    __syncthreads();
    const int row = tid >> 2, part = tid & 3;
    float s = 0.f;
    for (int c = part * 128; c < part * 128 + 128; ++c)
      s += b2f(hid[row * 512 + ((c + row * 8) & 511)]) * w2[c];
    s += __shfl_xor(s, 1);
    s += __shfl_xor(s, 2);
    if (part == 0) outp[m0 + row] = s + (head ? db2[0] : rb2[0]);
    __syncthreads();
  }
}

// ---------------- host ----------------
extern "C" void kernel_launch(void* const* d_in, const int* in_sizes, int n_in,
                              void* d_out, int out_size, void* d_ws, size_t ws_size,
                              hipStream_t stream) {
  const float* actions = (const float*)d_in[0];
  const float* obs     = (const float*)d_in[1];
  const float* eps     = (const float*)d_in[2];
  const float* h0      = (const float*)d_in[3];
  const float* z0      = (const float*)d_in[4];
  const float* Wih     = (const float*)d_in[5];
  const float* Whh     = (const float*)d_in[6];
  const float* bih     = (const float*)d_in[7];
  const float* bhh     = (const float*)d_in[8];
  const float* pW1     = (const float*)d_in[9];
  const float* pb1     = (const float*)d_in[10];
  const float* pW2     = (const float*)d_in[11];
  const float* pb2     = (const float*)d_in[12];
  const float* qW1     = (const float*)d_in[13];
  const float* qb1     = (const float*)d_in[14];
  const float* qW2     = (const float*)d_in[15];
  const float* qb2     = (const float*)d_in[16];
  const float* oW1     = (const float*)d_in[17];
  const float* ob1     = (const float*)d_in[18];
  const float* oW2     = (const float*)d_in[19];
  const float* ob2     = (const float*)d_in[20];
  const float* rW1     = (const float*)d_in[21];
  const float* rb1     = (const float*)d_in[22];
  const float* rW2     = (const float*)d_in[23];
  const float* rb2     = (const float*)d_in[24];
  const float* dW1     = (const float*)d_in[25];
  const float* db1     = (const float*)d_in[26];
  const float* dW2     = (const float*)d_in[27];
  const float* db2     = (const float*)d_in[28];

  float* out = (float*)d_out;
  float* out_h    = out;                  // [B,T,512]
  float* out_z    = out + 16777216;       // [B,T,32]
  float* out_obs  = out + 17825792;       // [B,T,256]
  float* out_rew  = out + 26214400;       // [B,T]
  float* out_done = out + 26247168;       // [B,T]
  float* out_prmu = out + 26279936;       // [B,T,32]
  float* out_prls = out + 27328512;       // [B,T,32]
  float* out_pomu = out + 28377088;       // [B,T,32]
  float* out_pols = out + 29425664;       // [B,T,32]

  char* w = (char*)d_ws;
  u16* WGT  = (u16*)(w + 0);          // [1536][576]
  u16* QW1T = (u16*)(w + 1769472);    // [512][768]
  u16* QW2T = (u16*)(w + 2555904);    // [64][512]
  u16* PW1T = (u16*)(w + 2621440);    // [512][512]
  u16* PW2T = (u16*)(w + 3145728);    // [64][512]
  u16* HW1T = (u16*)(w + 3211264);    // [1536][544] (obs|rew|done)
  u16* OW2T = (u16*)(w + 4882432);    // [256][512]
  u16* H0B  = (u16*)(w + 5144576);    // [128][512]
  u16* ACTB = (u16*)(w + 5275648);    // [B][T][16]
  u16* OBSB = (u16*)(w + 6324224);    // [B][T][256]
  u16* STALL= (u16*)(w + 23101440);   // [B*T][544]
  u16* Q1   = (u16*)(w + 58753024);   // [128][512]
  u16* Z0B  = (u16*)(w + 58884096);   // [128][32]
  unsigned* FLAGS = (unsigned*)(w + 58892288);  // [2][32][32] u32 = 8KB

  auto nb = [](int n) { return dim3((unsigned)((n + 255) / 256)); };

  k_zeroN<<<nb(2048), 256, 0, stream>>>(FLAGS, 2048);
  k_conv<<<nb(128 * 512), 256, 0, stream>>>(h0, H0B, 128 * 512);
  k_conv<<<nb(128 * 32), 256, 0, stream>>>(z0, Z0B, 128 * 32);
  k_conv<<<nb(128 * 256 * 16), 256, 0, stream>>>(actions, ACTB, 128 * 256 * 16);
  k_conv<<<nb(128 * 256 * 256), 256, 0, stream>>>(obs, OBSB, 128 * 256 * 256);
  k_tconv<<<nb(512 * 1536), 256, 0, stream>>>(Whh, WGT, 512, 1536, GK, 0, 0);
  k_tconv<<<nb(48 * 1536), 256, 0, stream>>>(Wih, WGT, 48, 1536, GK, 0, 512);
  k_padWg<<<nb(1536 * 16), 256, 0, stream>>>(WGT);
  k_tconv<<<nb(768 * 512), 256, 0, stream>>>(qW1, QW1T, 768, 512, 768, 0, 0);
  k_tconv<<<nb(512 * 64), 256, 0, stream>>>(qW2, QW2T, 512, 64, 512, 0, 0);
  k_tconv<<<nb(512 * 512), 256, 0, stream>>>(pW1, PW1T, 512, 512, 512, 0, 0);
  k_tconv<<<nb(512 * 64), 256, 0, stream>>>(pW2, PW2T, 512, 64, 512, 0, 0);
  k_tconv<<<nb(544 * 512), 256, 0, stream>>>(oW1, HW1T, 544, 512, STLD, 0, 0);
  k_tconv<<<nb(544 * 512), 256, 0, stream>>>(rW1, HW1T, 544, 512, STLD, 512, 0);
  k_tconv<<<nb(544 * 512), 256, 0, stream>>>(dW1, HW1T, 544, 512, STLD, 1024, 0);
  k_tconv<<<nb(512 * 256), 256, 0, stream>>>(oW2, OW2T, 512, 256, 512, 0, 0);

  SeqArgs sa;
  sa.h0b = H0B; sa.z0b = Z0B; sa.h0 = h0;
  sa.actb = ACTB; sa.obsb = OBSB; sa.eps = eps;
  sa.Wgt = WGT; sa.bih = bih; sa.bhh = bhh;
  sa.qW1t = QW1T; sa.qW2t = QW2T; sa.qb1 = qb1; sa.qb2 = qb2;
  sa.st_all = STALL; sa.q1 = Q1;
  sa.out_h = out_h; sa.out_z = out_z; sa.out_pomu = out_pomu; sa.out_pols = out_pols;
  sa.flags = FLAGS;
  k_seq<<<dim3(GRID), dim3(256), 0, stream>>>(sa);

  k_prior<<<512, 256, 0, stream>>>(STALL, PW1T, pb1, PW2T, pb2, out_prmu, out_prls);
  k_obs<<<512, 256, 0, stream>>>(STALL, HW1T, ob1, OW2T, ob2, out_obs);
  k_rewdone<<<512, 256, 0, stream>>>(STALL, HW1T, rb1, rW2, rb2, db1, dW2, db2,
                                     out_rew, out_done);
}